// Round 11
// baseline (135.601 us; speedup 1.0000x reference)
//
#include <hip/hip_runtime.h>

// Problem constants (from reference)
#define N_NODES 50000
#define N_EDGES 800000
#define IN_CH   128
#define HID_CH  128
#define OUT_CH  64

#define SCAN_B  1024
#define NB ((N_NODES + SCAN_B - 1) / SCAN_B)   // 49

#define GEMM1_TILES 782          // ceil(50000/64)
#define CSTRIDE 50048            // padded per-copy stride (ints)
#define HIST_TH_BLOCKS 391       // ceil(100000/256): 8 edges/thread

typedef __attribute__((ext_vector_type(8))) short v8s;
typedef __attribute__((ext_vector_type(4))) float v4f;

// ---------------------------------------------------------------------------
// bf16 helpers (RNE)
__device__ __forceinline__ unsigned bf16rne(float f) {
  unsigned u = __float_as_uint(f);
  return (u + 0x7fffu + ((u >> 16) & 1u)) >> 16;
}
__device__ __forceinline__ unsigned pack2bf(float a, float b) {
  return bf16rne(a) | (bf16rne(b) << 16);
}
__device__ __forceinline__ float bfhi_to_f(unsigned u) {   // high ushort
  return __uint_as_float(u & 0xffff0000u);
}
__device__ __forceinline__ float bflo_to_f(unsigned u) {   // low ushort
  return __uint_as_float(u << 16);
}

// ---------------------------------------------------------------------------
// Init: zero deg8[8][CSTRIDE] (blocks 0-390) + weight conversion (blocks 391+)
__global__ __launch_bounds__(256) void init_kernel(
    int* __restrict__ deg8,
    const float* __restrict__ W1, const float* __restrict__ W2,
    unsigned short* __restrict__ Wt1, unsigned short* __restrict__ Wt2) {
  int b = blockIdx.x;
  if (b < HIST_TH_BLOCKS) {
    int i = b * 256 + threadIdx.x;          // 100096 threads = (8*50048)/4
    *(uint4*)&deg8[i * 4] = make_uint4(0u, 0u, 0u, 0u);
  } else {
    int idx = (b - HIST_TH_BLOCKS) * 256 + threadIdx.x;
    if (idx < 128 * 128) {
      int k = idx >> 7, c = idx & 127;
      Wt1[c * 128 + k] = (unsigned short)bf16rne(W1[idx]);
    } else if (idx < 128 * 128 + 128 * 64) {
      int i2 = idx - 128 * 128;
      int k = i2 >> 6, c = i2 & 63;
      Wt2[c * 128 + k] = (unsigned short)bf16rne(W2[i2]);
    }
  }
}

// ---------------------------------------------------------------------------
// MFMA GEMM body: out[nrows x N] bf16 = A[nrows x 128] @ Bt^T, Bt=[N][128] bf16.
// A staged in LDS (fp32->bf16 converted if AFP32); B fragments read straight
// from global (Wt is 16-32KB, L1/L2 resident) -> LDS = 17.4KB only.
template <int N, bool AFP32>
__device__ __forceinline__ void gemm_body(
    int bid, const void* __restrict__ Av, const unsigned short* __restrict__ Bt,
    unsigned short* __restrict__ out, int nrows) {
  constexpr int KP = 136;
  __shared__ unsigned short sA[64 * KP];

  const int row0 = bid * 64;
  const int t = threadIdx.x;

  for (int i = t; i < 64 * 16; i += 256) {
    int r = i >> 4, ch = i & 15;
    uint4 v = make_uint4(0u, 0u, 0u, 0u);
    if (row0 + r < nrows) {
      if constexpr (AFP32) {
        const float* A = (const float*)Av;
        float4 f0 = *(const float4*)&A[(long)(row0 + r) * 128 + ch * 8];
        float4 f1 = *(const float4*)&A[(long)(row0 + r) * 128 + ch * 8 + 4];
        v.x = pack2bf(f0.x, f0.y); v.y = pack2bf(f0.z, f0.w);
        v.z = pack2bf(f1.x, f1.y); v.w = pack2bf(f1.z, f1.w);
      } else {
        const unsigned short* A = (const unsigned short*)Av;
        v = *(const uint4*)&A[(long)(row0 + r) * 128 + ch * 8];
      }
    }
    *(uint4*)&sA[r * KP + ch * 8] = v;
  }
  __syncthreads();

  const int wave = t >> 6, lane = t & 63;
  const int m0 = wave * 16;
  const int lr = lane & 15;
  const int kg = lane >> 4;

  constexpr int NT = N / 16;
  v4f acc[NT];
#pragma unroll
  for (int i = 0; i < NT; ++i) acc[i] = (v4f)(0.f);

#pragma unroll
  for (int ks = 0; ks < 4; ++ks) {
    const int k0 = ks * 32 + kg * 8;
    v8s a = *(const v8s*)&sA[(m0 + lr) * KP + k0];
#pragma unroll
    for (int nt = 0; nt < NT; ++nt) {
      v8s b = *(const v8s*)&Bt[(long)(nt * 16 + lr) * 128 + k0];
      acc[nt] = __builtin_amdgcn_mfma_f32_16x16x32_bf16(a, b, acc[nt], 0, 0, 0);
    }
  }

#pragma unroll
  for (int nt = 0; nt < NT; ++nt) {
#pragma unroll
    for (int i = 0; i < 4; ++i) {
      int gr = row0 + m0 + kg * 4 + i;
      if (gr < nrows)
        out[(long)gr * N + nt * 16 + lr] = (unsigned short)bf16rne(acc[nt][i]);
    }
  }
}

// ---------------------------------------------------------------------------
// Co-scheduled hist (8-way privatized degree histogram + rank) and GEMM1.
// blockIdx&1==0 -> GEMM1 tile; ==1 -> hist: thread t handles edges [8t,8t+8),
// all atomics go to copy k = t&7 (spreads per-node chains across 8 addresses).
__global__ __launch_bounds__(256) void hist_gemm1_kernel(
    const int* __restrict__ dst, int* __restrict__ deg8, int* __restrict__ rank,
    const float* __restrict__ x, const unsigned short* __restrict__ Wt1,
    unsigned short* __restrict__ hw1) {
  int role = blockIdx.x & 1;
  int gid  = blockIdx.x >> 1;
  if (role == 0) {
    gemm_body<128, true>(gid, x, Wt1, hw1, N_NODES);
  } else {
    long t = (long)gid * 256 + threadIdx.x;
    long base = t * 8;
    if (base < N_EDGES) {
      int* degk = deg8 + ((int)t & 7) * CSTRIDE;
      int4 d0 = *(const int4*)&dst[base];
      int4 d1 = *(const int4*)&dst[base + 4];
      int r0 = atomicAdd(&degk[d0.x], 1);
      int r1 = atomicAdd(&degk[d0.y], 1);
      int r2 = atomicAdd(&degk[d0.z], 1);
      int r3 = atomicAdd(&degk[d0.w], 1);
      int r4 = atomicAdd(&degk[d1.x], 1);
      int r5 = atomicAdd(&degk[d1.y], 1);
      int r6 = atomicAdd(&degk[d1.z], 1);
      int r7 = atomicAdd(&degk[d1.w], 1);
      *(int4*)&rank[base]     = make_int4(r0, r1, r2, r3);
      *(int4*)&rank[base + 4] = make_int4(r4, r5, r6, r7);
    }
  }
}

// ---------------------------------------------------------------------------
// CSR step 2a: combine 8 copies -> deg, per-copy exclusive offsets off8,
// dinv, and per-chunk sums for the scan.
__global__ __launch_bounds__(SCAN_B) void scan_partial_kernel(
    const int* __restrict__ deg8, int* __restrict__ deg, int* __restrict__ off8,
    int* __restrict__ bsums, float* __restrict__ dinv) {
  __shared__ int sh[SCAN_B];
  int t = threadIdx.x;
  int g = blockIdx.x * SCAN_B + t;
  int c[8];
#pragma unroll
  for (int k = 0; k < 8; ++k)
    c[k] = (g < N_NODES) ? deg8[k * CSTRIDE + g] : 0;
  int o[8];
  o[0] = 0;
#pragma unroll
  for (int k = 1; k < 8; ++k) o[k] = o[k - 1] + c[k - 1];
  int v = o[7] + c[7];
  if (g < N_NODES) {
    deg[g] = v;
    dinv[g] = rsqrtf((float)v + 1.0f);
    *(int4*)&off8[(long)g * 8]     = make_int4(o[0], o[1], o[2], o[3]);
    *(int4*)&off8[(long)g * 8 + 4] = make_int4(o[4], o[5], o[6], o[7]);
  }
  sh[t] = v;
  __syncthreads();
  for (int off = SCAN_B / 2; off > 0; off >>= 1) {
    if (t < off) sh[t] += sh[t + off];
    __syncthreads();
  }
  if (t == 0) bsums[blockIdx.x] = sh[0];
}

// CSR step 2b: per-chunk exclusive scan; block offset via wave reduce.
// Also emits base8[n][k] = row_ptr[n] + off8[n][k] for the place pass.
__global__ __launch_bounds__(SCAN_B) void scan_final_kernel(
    const int* __restrict__ deg, const int* __restrict__ bsums,
    const int* __restrict__ off8, int* __restrict__ row_ptr,
    int* __restrict__ base8) {
  __shared__ int sh[SCAN_B];
  __shared__ int s_off;
  int t = threadIdx.x;
  int g = blockIdx.x * SCAN_B + t;
  int v = (g < N_NODES) ? deg[g] : 0;
  sh[t] = v;
  if (t < 64) {
    int pv = (t < blockIdx.x && t < NB) ? bsums[t] : 0;
#pragma unroll
    for (int off = 32; off > 0; off >>= 1) pv += __shfl_down(pv, off);
    if (t == 0) s_off = pv;
  }
  if (g == 0) row_ptr[N_NODES] = N_EDGES;
  __syncthreads();
  for (int off = 1; off < SCAN_B; off <<= 1) {
    int add = (t >= off) ? sh[t - off] : 0;
    __syncthreads();
    sh[t] += add;
    __syncthreads();
  }
  int excl = sh[t] - v + s_off;
  if (g < N_NODES) {
    row_ptr[g] = excl;
    int4 a = *(const int4*)&off8[(long)g * 8];
    int4 b = *(const int4*)&off8[(long)g * 8 + 4];
    a.x += excl; a.y += excl; a.z += excl; a.w += excl;
    b.x += excl; b.y += excl; b.z += excl; b.w += excl;
    *(int4*)&base8[(long)g * 8]     = a;
    *(int4*)&base8[(long)g * 8 + 4] = b;
  }
}

// CSR step 3: place src ids. Thread t owns edges [8t,8t+8) (same mapping as
// hist, so copy k = t&7); pos = base8[dst*8+k] + rank[e]. Atomic-free.
__global__ __launch_bounds__(256) void place_kernel(
    const int* __restrict__ src, const int* __restrict__ dst,
    const int* __restrict__ rank, const int* __restrict__ base8,
    int* __restrict__ csr_src) {
  long t = (long)blockIdx.x * 256 + threadIdx.x;
  long base = t * 8;
  if (base < N_EDGES) {
    int k = (int)t & 7;
    int4 d0 = *(const int4*)&dst[base];
    int4 d1 = *(const int4*)&dst[base + 4];
    int4 r0 = *(const int4*)&rank[base];
    int4 r1 = *(const int4*)&rank[base + 4];
    int4 s0 = *(const int4*)&src[base];
    int4 s1 = *(const int4*)&src[base + 4];
    csr_src[base8[(long)d0.x * 8 + k] + r0.x] = s0.x;
    csr_src[base8[(long)d0.y * 8 + k] + r0.y] = s0.y;
    csr_src[base8[(long)d0.z * 8 + k] + r0.z] = s0.z;
    csr_src[base8[(long)d0.w * 8 + k] + r0.w] = s0.w;
    csr_src[base8[(long)d1.x * 8 + k] + r1.x] = s1.x;
    csr_src[base8[(long)d1.y * 8 + k] + r1.y] = s1.y;
    csr_src[base8[(long)d1.z * 8 + k] + r1.z] = s1.z;
    csr_src[base8[(long)d1.w * 8 + k] + r1.w] = s1.w;
  }
}

// ---------------------------------------------------------------------------
// Standalone GEMM2 wrapper
__global__ __launch_bounds__(256) void gemm2_kernel(
    const unsigned short* __restrict__ A, const unsigned short* __restrict__ Wt2,
    unsigned short* __restrict__ hw2) {
  gemm_body<64, false>(blockIdx.x, A, Wt2, hw2, N_NODES);
}

// ---------------------------------------------------------------------------
// Layer-1 aggregation, one wave per node, 2 edges per VMEM instruction:
// lanes 0-31 own even edge of a pair, lanes 32-63 the odd edge.
// C=128: lane handles 4 channels (uint2 = 4 bf16). h1 output bf16 packed.
__global__ __launch_bounds__(256) void agg128_kernel(
    const int* __restrict__ row_ptr, const int* __restrict__ csr_src,
    const float* __restrict__ dinv, const unsigned* __restrict__ hw,  // [N][64] u32
    const float* __restrict__ bias, unsigned* __restrict__ h1out) {   // [N][64] u32
  int n = (blockIdx.x * 256 + threadIdx.x) >> 6;
  int lane = threadIdx.x & 63;
  if (n >= N_NODES) return;
  const int half = lane >> 5;      // which edge of the pair
  const int lc = lane & 31;        // channel quad: ch 4lc..4lc+3
  const int start = row_ptr[n];
  const int deg = row_ptr[n + 1] - start;
  const int np = (deg + 1) >> 1;   // pairs (last may be half-valid)

  float a0 = 0.f, a1 = 0.f, a2 = 0.f, a3 = 0.f;

#define LS(i, pp) { int tt = 2 * (pp) + half; int cl = tt < deg ? tt : deg - 1; \
                    s##i = csr_src[start + cl]; m##i = (tt < deg) ? 1.f : 0.f; }
  int s0, s1, s2, s3;
  float m0, m1, m2, m3;
  if (np > 0) { LS(0, 0) LS(1, 1) LS(2, 2) LS(3, 3) }
  for (int p = 0; p < np; p += 4) {
    int q0 = s0, q1 = s1, q2 = s2, q3 = s3;
    float f0 = m0, f1 = m1, f2 = m2, f3 = m3;
    int pn = p + 4;
    if (pn < np) { LS(0, pn) LS(1, pn + 1) LS(2, pn + 2) LS(3, pn + 3) }
    float w0 = dinv[q0] * f0;
    float w1 = dinv[q1] * f1;
    float w2 = dinv[q2] * f2;
    float w3 = dinv[q3] * f3;
    uint2 u0 = *(const uint2*)&hw[(long)q0 * 64 + 2 * lc];
    uint2 u1 = *(const uint2*)&hw[(long)q1 * 64 + 2 * lc];
    uint2 u2 = *(const uint2*)&hw[(long)q2 * 64 + 2 * lc];
    uint2 u3 = *(const uint2*)&hw[(long)q3 * 64 + 2 * lc];
    a0 = fmaf(bflo_to_f(u0.x), w0, a0); a1 = fmaf(bfhi_to_f(u0.x), w0, a1);
    a2 = fmaf(bflo_to_f(u0.y), w0, a2); a3 = fmaf(bfhi_to_f(u0.y), w0, a3);
    a0 = fmaf(bflo_to_f(u1.x), w1, a0); a1 = fmaf(bfhi_to_f(u1.x), w1, a1);
    a2 = fmaf(bflo_to_f(u1.y), w1, a2); a3 = fmaf(bfhi_to_f(u1.y), w1, a3);
    a0 = fmaf(bflo_to_f(u2.x), w2, a0); a1 = fmaf(bfhi_to_f(u2.x), w2, a1);
    a2 = fmaf(bflo_to_f(u2.y), w2, a2); a3 = fmaf(bfhi_to_f(u2.y), w2, a3);
    a0 = fmaf(bflo_to_f(u3.x), w3, a0); a1 = fmaf(bfhi_to_f(u3.x), w3, a1);
    a2 = fmaf(bflo_to_f(u3.y), w3, a2); a3 = fmaf(bfhi_to_f(u3.y), w3, a3);
  }
#undef LS

  a0 += __shfl_xor(a0, 32);
  a1 += __shfl_xor(a1, 32);
  a2 += __shfl_xor(a2, 32);
  a3 += __shfl_xor(a3, 32);

  float dn = dinv[n];
  float sn = dn * dn;
  uint2 uh = *(const uint2*)&hw[(long)n * 64 + 2 * lc];
  float4 bb = *(const float4*)&bias[4 * lc];
  float o0 = fmaxf(fmaf(bflo_to_f(uh.x), sn, a0 * dn) + bb.x, 0.f);
  float o1 = fmaxf(fmaf(bfhi_to_f(uh.x), sn, a1 * dn) + bb.y, 0.f);
  float o2 = fmaxf(fmaf(bflo_to_f(uh.y), sn, a2 * dn) + bb.z, 0.f);
  float o3 = fmaxf(fmaf(bfhi_to_f(uh.y), sn, a3 * dn) + bb.w, 0.f);
  if (half == 0) {
    uint2 pz;
    pz.x = pack2bf(o0, o1);
    pz.y = pack2bf(o2, o3);
    *(uint2*)&h1out[(long)n * 64 + 2 * lc] = pz;
  }
}

// Layer-2 aggregation: lane handles 2 channels (u32 = 2 bf16); fp32 output.
__global__ __launch_bounds__(256) void agg64_kernel(
    const int* __restrict__ row_ptr, const int* __restrict__ csr_src,
    const float* __restrict__ dinv, const unsigned* __restrict__ hw,  // [N][32] u32
    const float* __restrict__ bias, float* __restrict__ out) {
  int n = (blockIdx.x * 256 + threadIdx.x) >> 6;
  int lane = threadIdx.x & 63;
  if (n >= N_NODES) return;
  const int half = lane >> 5;
  const int lc = lane & 31;        // channel pair: ch 2lc, 2lc+1
  const int start = row_ptr[n];
  const int deg = row_ptr[n + 1] - start;
  const int np = (deg + 1) >> 1;

  float a0 = 0.f, a1 = 0.f;

#define LS(i, pp) { int tt = 2 * (pp) + half; int cl = tt < deg ? tt : deg - 1; \
                    s##i = csr_src[start + cl]; m##i = (tt < deg) ? 1.f : 0.f; }
  int s0, s1, s2, s3;
  float m0, m1, m2, m3;
  if (np > 0) { LS(0, 0) LS(1, 1) LS(2, 2) LS(3, 3) }
  for (int p = 0; p < np; p += 4) {
    int q0 = s0, q1 = s1, q2 = s2, q3 = s3;
    float f0 = m0, f1 = m1, f2 = m2, f3 = m3;
    int pn = p + 4;
    if (pn < np) { LS(0, pn) LS(1, pn + 1) LS(2, pn + 2) LS(3, pn + 3) }
    float w0 = dinv[q0] * f0;
    float w1 = dinv[q1] * f1;
    float w2 = dinv[q2] * f2;
    float w3 = dinv[q3] * f3;
    unsigned u0 = hw[(long)q0 * 32 + lc];
    unsigned u1 = hw[(long)q1 * 32 + lc];
    unsigned u2 = hw[(long)q2 * 32 + lc];
    unsigned u3 = hw[(long)q3 * 32 + lc];
    a0 = fmaf(bflo_to_f(u0), w0, a0); a1 = fmaf(bfhi_to_f(u0), w0, a1);
    a0 = fmaf(bflo_to_f(u1), w1, a0); a1 = fmaf(bfhi_to_f(u1), w1, a1);
    a0 = fmaf(bflo_to_f(u2), w2, a0); a1 = fmaf(bfhi_to_f(u2), w2, a1);
    a0 = fmaf(bflo_to_f(u3), w3, a0); a1 = fmaf(bfhi_to_f(u3), w3, a1);
  }
#undef LS

  a0 += __shfl_xor(a0, 32);
  a1 += __shfl_xor(a1, 32);

  float dn = dinv[n];
  float sn = dn * dn;
  unsigned uh = hw[(long)n * 32 + lc];
  float2 bb = *(const float2*)&bias[2 * lc];
  float o0 = fmaxf(fmaf(bflo_to_f(uh), sn, a0 * dn) + bb.x, 0.f);
  float o1 = fmaxf(fmaf(bfhi_to_f(uh), sn, a1 * dn) + bb.y, 0.f);
  if (half == 0) {
    *(float2*)&out[(long)n * 64 + 2 * lc] = make_float2(o0, o1);
  }
}

// ---------------------------------------------------------------------------
extern "C" void kernel_launch(void* const* d_in, const int* in_sizes, int n_in,
                              void* d_out, int out_size, void* d_ws, size_t ws_size,
                              hipStream_t stream) {
  const float* x  = (const float*)d_in[0];
  const int*   ei = (const int*)d_in[1];
  const float* W1 = (const float*)d_in[2];
  const float* b1 = (const float*)d_in[3];
  const float* W2 = (const float*)d_in[4];
  const float* b2 = (const float*)d_in[5];
  float* out = (float*)d_out;

  const int* src = ei;             // edge_index[0]
  const int* dst = ei + N_EDGES;   // edge_index[1]

  // Workspace layout (bytes; every chunk is a multiple of 256B)
  char* ws = (char*)d_ws;
  int*   deg8    = (int*)ws;                     ws += (size_t)8 * CSTRIDE * 4;  // 1.6MB
  int*   deg     = (int*)ws;                     ws += 50048 * 4;
  float* dinv    = (float*)ws;                   ws += 50048 * 4;
  int*   row_ptr = (int*)ws;                     ws += 50048 * 4;
  int*   bsums   = (int*)ws;                     ws += 64 * 4;
  int*   off8    = (int*)ws;                     ws += (size_t)50048 * 8 * 4;    // 1.6MB
  int*   base8   = (int*)ws;                     ws += (size_t)50048 * 8 * 4;    // 1.6MB
  int*   rank    = (int*)ws;                     ws += (size_t)N_EDGES * 4;
  int*   csr_src = (int*)ws;                     ws += (size_t)N_EDGES * 4;
  unsigned short* Wt1 = (unsigned short*)ws;     ws += 128 * 128 * 2;
  unsigned short* Wt2 = (unsigned short*)ws;     ws += 64 * 128 * 2;
  unsigned short* hw1 = (unsigned short*)ws;     ws += (size_t)N_NODES * 128 * 2;
  unsigned*       h1  = (unsigned*)ws;           ws += (size_t)N_NODES * 64 * 4;
  unsigned short* hw2 = (unsigned short*)ws;     ws += (size_t)N_NODES * 64 * 2;

  // ---- Init (zero deg8 + weight conversion) ----
  init_kernel<<<HIST_TH_BLOCKS + 96, 256, 0, stream>>>(deg8, W1, W2, Wt1, Wt2);

  // ---- hist (8-way privatized, 8 edges/thread) co-scheduled with GEMM1 ----
  hist_gemm1_kernel<<<GEMM1_TILES * 2, 256, 0, stream>>>(
      dst, deg8, rank, x, Wt1, hw1);

  // ---- CSR combine + scan + place ----
  scan_partial_kernel<<<NB, SCAN_B, 0, stream>>>(deg8, deg, off8, bsums, dinv);
  scan_final_kernel<<<NB, SCAN_B, 0, stream>>>(deg, bsums, off8, row_ptr, base8);
  place_kernel<<<HIST_TH_BLOCKS, 256, 0, stream>>>(src, dst, rank, base8, csr_src);

  // ---- Layer 1 aggregation ----
  agg128_kernel<<<(N_NODES * 64 + 255) / 256, 256, 0, stream>>>(
      row_ptr, csr_src, dinv, (const unsigned*)hw1, b1, h1);

  // ---- Layer 2 GEMM ----
  gemm2_kernel<<<GEMM1_TILES, 256, 0, stream>>>(
      (const unsigned short*)h1, Wt2, hw2);

  // ---- Layer 2 aggregation ----
  agg64_kernel<<<(N_NODES * 64 + 255) / 256, 256, 0, stream>>>(
      row_ptr, csr_src, dinv, (const unsigned*)hw2, b2, out);
}

// Round 13
// 133.833 us; speedup vs baseline: 1.0132x; 1.0132x over previous
//
#include <hip/hip_runtime.h>

// Problem constants (from reference)
#define N_NODES 50000
#define N_EDGES 800000
#define IN_CH   128
#define HID_CH  128
#define OUT_CH  64

#define SCAN_B  1024
#define NB ((N_NODES + SCAN_B - 1) / SCAN_B)   // 49

#define GEMM1_TILES 782          // ceil(50000/64)

typedef __attribute__((ext_vector_type(8))) short v8s;
typedef __attribute__((ext_vector_type(4))) float v4f;

// ---------------------------------------------------------------------------
// bf16 helpers (RNE)
__device__ __forceinline__ unsigned bf16rne(float f) {
  unsigned u = __float_as_uint(f);
  return (u + 0x7fffu + ((u >> 16) & 1u)) >> 16;
}
__device__ __forceinline__ unsigned pack2bf(float a, float b) {
  return bf16rne(a) | (bf16rne(b) << 16);
}
__device__ __forceinline__ float bfhi_to_f(unsigned u) {   // high ushort
  return __uint_as_float(u & 0xffff0000u);
}
__device__ __forceinline__ float bflo_to_f(unsigned u) {   // low ushort
  return __uint_as_float(u << 16);
}

// ---------------------------------------------------------------------------
// Init: zero deg[] (blocks 0-48) + convert both weight matrices (blocks 49+)
__global__ __launch_bounds__(256) void init_kernel(
    int* __restrict__ deg,
    const float* __restrict__ W1, const float* __restrict__ W2,
    unsigned short* __restrict__ Wt1, unsigned short* __restrict__ Wt2) {
  int b = blockIdx.x;
  if (b < 49) {
    int i = b * 256 + threadIdx.x;
    if (i < 50048 / 4) *(uint4*)&deg[i * 4] = make_uint4(0u, 0u, 0u, 0u);
  } else {
    int idx = (b - 49) * 256 + threadIdx.x;
    if (idx < 128 * 128) {
      int k = idx >> 7, c = idx & 127;
      Wt1[c * 128 + k] = (unsigned short)bf16rne(W1[idx]);
    } else if (idx < 128 * 128 + 128 * 64) {
      int i2 = idx - 128 * 128;
      int k = i2 >> 6, c = i2 & 63;
      Wt2[c * 128 + k] = (unsigned short)bf16rne(W2[i2]);
    }
  }
}

// ---------------------------------------------------------------------------
// MFMA GEMM body: out[nrows x N] bf16 = A[nrows x 128] @ Bt^T, Bt=[N][128] bf16.
// A staged in LDS (fp32->bf16 converted if AFP32); B fragments read straight
// from global (Wt is 16-32KB, L1/L2 resident) -> LDS = 17.4KB only.
template <int N, bool AFP32>
__device__ __forceinline__ void gemm_body(
    int bid, const void* __restrict__ Av, const unsigned short* __restrict__ Bt,
    unsigned short* __restrict__ out, int nrows) {
  constexpr int KP = 136;
  __shared__ unsigned short sA[64 * KP];

  const int row0 = bid * 64;
  const int t = threadIdx.x;

  for (int i = t; i < 64 * 16; i += 256) {
    int r = i >> 4, ch = i & 15;
    uint4 v = make_uint4(0u, 0u, 0u, 0u);
    if (row0 + r < nrows) {
      if constexpr (AFP32) {
        const float* A = (const float*)Av;
        float4 f0 = *(const float4*)&A[(long)(row0 + r) * 128 + ch * 8];
        float4 f1 = *(const float4*)&A[(long)(row0 + r) * 128 + ch * 8 + 4];
        v.x = pack2bf(f0.x, f0.y); v.y = pack2bf(f0.z, f0.w);
        v.z = pack2bf(f1.x, f1.y); v.w = pack2bf(f1.z, f1.w);
      } else {
        const unsigned short* A = (const unsigned short*)Av;
        v = *(const uint4*)&A[(long)(row0 + r) * 128 + ch * 8];
      }
    }
    *(uint4*)&sA[r * KP + ch * 8] = v;
  }
  __syncthreads();

  const int wave = t >> 6, lane = t & 63;
  const int m0 = wave * 16;
  const int lr = lane & 15;
  const int kg = lane >> 4;

  constexpr int NT = N / 16;
  v4f acc[NT];
#pragma unroll
  for (int i = 0; i < NT; ++i) acc[i] = (v4f)(0.f);

#pragma unroll
  for (int ks = 0; ks < 4; ++ks) {
    const int k0 = ks * 32 + kg * 8;
    v8s a = *(const v8s*)&sA[(m0 + lr) * KP + k0];
#pragma unroll
    for (int nt = 0; nt < NT; ++nt) {
      v8s b = *(const v8s*)&Bt[(long)(nt * 16 + lr) * 128 + k0];
      acc[nt] = __builtin_amdgcn_mfma_f32_16x16x32_bf16(a, b, acc[nt], 0, 0, 0);
    }
  }

#pragma unroll
  for (int nt = 0; nt < NT; ++nt) {
#pragma unroll
    for (int i = 0; i < 4; ++i) {
      int gr = row0 + m0 + kg * 4 + i;
      if (gr < nrows)
        out[(long)gr * N + nt * 16 + lr] = (unsigned short)bf16rne(acc[nt][i]);
    }
  }
}

// ---------------------------------------------------------------------------
// Co-scheduled hist (degree histogram + rank) and GEMM1.
// blockIdx&1==0 -> GEMM1 tile; ==1 -> hist, 8 edges/thread batched atomics.
__global__ __launch_bounds__(256) void hist_gemm1_kernel(
    const int* __restrict__ dst, int* __restrict__ deg, int* __restrict__ rank,
    const float* __restrict__ x, const unsigned short* __restrict__ Wt1,
    unsigned short* __restrict__ hw1) {
  int role = blockIdx.x & 1;
  int gid  = blockIdx.x >> 1;
  if (role == 0) {
    gemm_body<128, true>(gid, x, Wt1, hw1, N_NODES);
  } else {
    long base = ((long)gid * 256 + threadIdx.x) * 8;
    if (base < N_EDGES) {
      int4 d0 = *(const int4*)&dst[base];
      int4 d1 = *(const int4*)&dst[base + 4];
      int r0 = atomicAdd(&deg[d0.x], 1);
      int r1 = atomicAdd(&deg[d0.y], 1);
      int r2 = atomicAdd(&deg[d0.z], 1);
      int r3 = atomicAdd(&deg[d0.w], 1);
      int r4 = atomicAdd(&deg[d1.x], 1);
      int r5 = atomicAdd(&deg[d1.y], 1);
      int r6 = atomicAdd(&deg[d1.z], 1);
      int r7 = atomicAdd(&deg[d1.w], 1);
      *(int4*)&rank[base]     = make_int4(r0, r1, r2, r3);
      *(int4*)&rank[base + 4] = make_int4(r4, r5, r6, r7);
    }
  }
}

// ---------------------------------------------------------------------------
// CSR build step 2a: per-chunk sums + dinv (fused; both read deg)
__global__ __launch_bounds__(SCAN_B) void scan_partial_kernel(
    const int* __restrict__ deg, int* __restrict__ bsums, float* __restrict__ dinv) {
  __shared__ int sh[SCAN_B];
  int t = threadIdx.x;
  int g = blockIdx.x * SCAN_B + t;
  int v = (g < N_NODES) ? deg[g] : 0;
  sh[t] = v;
  if (g < N_NODES) dinv[g] = rsqrtf((float)v + 1.0f);
  __syncthreads();
  for (int off = SCAN_B / 2; off > 0; off >>= 1) {
    if (t < off) sh[t] += sh[t + off];
    __syncthreads();
  }
  if (t == 0) bsums[blockIdx.x] = sh[0];
}

// CSR build step 2b: per-chunk exclusive scan; block offset via wave reduce.
__global__ __launch_bounds__(SCAN_B) void scan_final_kernel(
    const int* __restrict__ deg, const int* __restrict__ bsums,
    int* __restrict__ row_ptr) {
  __shared__ int sh[SCAN_B];
  __shared__ int s_off;
  int t = threadIdx.x;
  int g = blockIdx.x * SCAN_B + t;
  int v = (g < N_NODES) ? deg[g] : 0;
  sh[t] = v;
  if (t < 64) {
    int pv = (t < blockIdx.x && t < NB) ? bsums[t] : 0;
#pragma unroll
    for (int off = 32; off > 0; off >>= 1) pv += __shfl_down(pv, off);
    if (t == 0) s_off = pv;
  }
  if (g == 0) row_ptr[N_NODES] = N_EDGES;
  __syncthreads();
  for (int off = 1; off < SCAN_B; off <<= 1) {
    int add = (t >= off) ? sh[t - off] : 0;
    __syncthreads();
    sh[t] += add;
    __syncthreads();
  }
  int excl = sh[t] - v + s_off;
  if (g < N_NODES) row_ptr[g] = excl;
}

// CSR build step 3: place src ids, 8 edges/thread (atomic-free).
__global__ __launch_bounds__(256) void place_kernel(
    const int* __restrict__ src, const int* __restrict__ dst,
    const int* __restrict__ rank, const int* __restrict__ row_ptr,
    int* __restrict__ csr_src) {
  long base = ((long)blockIdx.x * 256 + threadIdx.x) * 8;
  if (base < N_EDGES) {
    int4 d0 = *(const int4*)&dst[base];
    int4 d1 = *(const int4*)&dst[base + 4];
    int4 r0 = *(const int4*)&rank[base];
    int4 r1 = *(const int4*)&rank[base + 4];
    int4 s0 = *(const int4*)&src[base];
    int4 s1 = *(const int4*)&src[base + 4];
    csr_src[row_ptr[d0.x] + r0.x] = s0.x;
    csr_src[row_ptr[d0.y] + r0.y] = s0.y;
    csr_src[row_ptr[d0.z] + r0.z] = s0.z;
    csr_src[row_ptr[d0.w] + r0.w] = s0.w;
    csr_src[row_ptr[d1.x] + r1.x] = s1.x;
    csr_src[row_ptr[d1.y] + r1.y] = s1.y;
    csr_src[row_ptr[d1.z] + r1.z] = s1.z;
    csr_src[row_ptr[d1.w] + r1.w] = s1.w;
  }
}

// ---------------------------------------------------------------------------
// Standalone GEMM2 wrapper
__global__ __launch_bounds__(256) void gemm2_kernel(
    const unsigned short* __restrict__ A, const unsigned short* __restrict__ Wt2,
    unsigned short* __restrict__ hw2) {
  gemm_body<64, false>(blockIdx.x, A, Wt2, hw2, N_NODES);
}

// ---------------------------------------------------------------------------
// Accumulate helpers (functions, not macros — avoids u.w token capture)
__device__ __forceinline__ void acc8(uint4 u, float w, float* a) {
  a[0] = fmaf(bflo_to_f(u.x), w, a[0]); a[1] = fmaf(bfhi_to_f(u.x), w, a[1]);
  a[2] = fmaf(bflo_to_f(u.y), w, a[2]); a[3] = fmaf(bfhi_to_f(u.y), w, a[3]);
  a[4] = fmaf(bflo_to_f(u.z), w, a[4]); a[5] = fmaf(bfhi_to_f(u.z), w, a[5]);
  a[6] = fmaf(bflo_to_f(u.w), w, a[6]); a[7] = fmaf(bfhi_to_f(u.w), w, a[7]);
}
__device__ __forceinline__ void acc4(uint2 u, float w, float* a) {
  a[0] = fmaf(bflo_to_f(u.x), w, a[0]); a[1] = fmaf(bfhi_to_f(u.x), w, a[1]);
  a[2] = fmaf(bflo_to_f(u.y), w, a[2]); a[3] = fmaf(bfhi_to_f(u.y), w, a[3]);
}

// ---------------------------------------------------------------------------
// Layer-1 aggregation, one wave per node, QUARTER-wave per edge:
// 4 edges per VMEM instruction. Quarter q (lane>>4) owns edge 4p+q; each lane
// loads 16B = 8 channels (uint4). Combine via shfl_xor 16 then 32.
__global__ __launch_bounds__(256) void agg128_kernel(
    const int* __restrict__ row_ptr, const int* __restrict__ csr_src,
    const float* __restrict__ dinv, const unsigned* __restrict__ hw,  // [N][64] u32
    const float* __restrict__ bias, unsigned* __restrict__ h1out) {   // [N][64] u32
  int n = (blockIdx.x * 256 + threadIdx.x) >> 6;
  int lane = threadIdx.x & 63;
  if (n >= N_NODES) return;
  const int q  = lane >> 4;        // edge slot in group of 4
  const int lc = lane & 15;        // channel octet: ch 8lc..8lc+7
  const int start = row_ptr[n];
  const int deg = row_ptr[n + 1] - start;
  const int ng = (deg + 3) >> 2;   // groups of 4 edges

  float a[8] = {0.f, 0.f, 0.f, 0.f, 0.f, 0.f, 0.f, 0.f};

#define LS(i, pp) { int tt = 4 * (pp) + q; int cl = tt < deg ? tt : deg - 1; \
                    s##i = csr_src[start + cl]; m##i = (tt < deg) ? 1.f : 0.f; }
  int s0, s1, s2, s3;
  float m0, m1, m2, m3;
  if (ng > 0) { LS(0, 0) LS(1, 1) LS(2, 2) LS(3, 3) }
  for (int p = 0; p < ng; p += 4) {
    int e0 = s0, e1 = s1, e2 = s2, e3 = s3;
    float f0 = m0, f1 = m1, f2 = m2, f3 = m3;
    int pn = p + 4;
    if (pn < ng) { LS(0, pn) LS(1, pn + 1) LS(2, pn + 2) LS(3, pn + 3) }
    float w0 = dinv[e0] * f0;
    float w1 = dinv[e1] * f1;
    float w2 = dinv[e2] * f2;
    float w3 = dinv[e3] * f3;
    uint4 u0 = *(const uint4*)&hw[(long)e0 * 64 + 4 * lc];
    uint4 u1 = *(const uint4*)&hw[(long)e1 * 64 + 4 * lc];
    uint4 u2 = *(const uint4*)&hw[(long)e2 * 64 + 4 * lc];
    uint4 u3 = *(const uint4*)&hw[(long)e3 * 64 + 4 * lc];
    acc8(u0, w0, a); acc8(u1, w1, a); acc8(u2, w2, a); acc8(u3, w3, a);
  }
#undef LS

  // combine the four quarter-wave partial sums
#pragma unroll
  for (int i = 0; i < 8; ++i) a[i] += __shfl_xor(a[i], 16);
#pragma unroll
  for (int i = 0; i < 8; ++i) a[i] += __shfl_xor(a[i], 32);

  float dn = dinv[n];
  float sn = dn * dn;
  uint4 uh = *(const uint4*)&hw[(long)n * 64 + 4 * lc];
  float4 ba = *(const float4*)&bias[8 * lc];
  float4 bb = *(const float4*)&bias[8 * lc + 4];
  float o0 = fmaxf(fmaf(bflo_to_f(uh.x), sn, a[0] * dn) + ba.x, 0.f);
  float o1 = fmaxf(fmaf(bfhi_to_f(uh.x), sn, a[1] * dn) + ba.y, 0.f);
  float o2 = fmaxf(fmaf(bflo_to_f(uh.y), sn, a[2] * dn) + ba.z, 0.f);
  float o3 = fmaxf(fmaf(bfhi_to_f(uh.y), sn, a[3] * dn) + ba.w, 0.f);
  float o4 = fmaxf(fmaf(bflo_to_f(uh.z), sn, a[4] * dn) + bb.x, 0.f);
  float o5 = fmaxf(fmaf(bfhi_to_f(uh.z), sn, a[5] * dn) + bb.y, 0.f);
  float o6 = fmaxf(fmaf(bflo_to_f(uh.w), sn, a[6] * dn) + bb.z, 0.f);
  float o7 = fmaxf(fmaf(bfhi_to_f(uh.w), sn, a[7] * dn) + bb.w, 0.f);
  if (q == 0) {
    uint4 pz;
    pz.x = pack2bf(o0, o1);
    pz.y = pack2bf(o2, o3);
    pz.z = pack2bf(o4, o5);
    pz.w = pack2bf(o6, o7);
    *(uint4*)&h1out[(long)n * 64 + 4 * lc] = pz;
  }
}

// Layer-2 aggregation, quarter-wave: 4 edges per VMEM instruction; lane loads
// 8B = 4 channels (uint2). fp32 output.
__global__ __launch_bounds__(256) void agg64_kernel(
    const int* __restrict__ row_ptr, const int* __restrict__ csr_src,
    const float* __restrict__ dinv, const unsigned* __restrict__ hw,  // [N][32] u32
    const float* __restrict__ bias, float* __restrict__ out) {
  int n = (blockIdx.x * 256 + threadIdx.x) >> 6;
  int lane = threadIdx.x & 63;
  if (n >= N_NODES) return;
  const int q  = lane >> 4;
  const int lc = lane & 15;        // channel quad: ch 4lc..4lc+3
  const int start = row_ptr[n];
  const int deg = row_ptr[n + 1] - start;
  const int ng = (deg + 3) >> 2;

  float a[4] = {0.f, 0.f, 0.f, 0.f};

#define LS(i, pp) { int tt = 4 * (pp) + q; int cl = tt < deg ? tt : deg - 1; \
                    s##i = csr_src[start + cl]; m##i = (tt < deg) ? 1.f : 0.f; }
  int s0, s1, s2, s3;
  float m0, m1, m2, m3;
  if (ng > 0) { LS(0, 0) LS(1, 1) LS(2, 2) LS(3, 3) }
  for (int p = 0; p < ng; p += 4) {
    int e0 = s0, e1 = s1, e2 = s2, e3 = s3;
    float f0 = m0, f1 = m1, f2 = m2, f3 = m3;
    int pn = p + 4;
    if (pn < ng) { LS(0, pn) LS(1, pn + 1) LS(2, pn + 2) LS(3, pn + 3) }
    float w0 = dinv[e0] * f0;
    float w1 = dinv[e1] * f1;
    float w2 = dinv[e2] * f2;
    float w3 = dinv[e3] * f3;
    uint2 u0 = *(const uint2*)&hw[(long)e0 * 32 + 2 * lc];
    uint2 u1 = *(const uint2*)&hw[(long)e1 * 32 + 2 * lc];
    uint2 u2 = *(const uint2*)&hw[(long)e2 * 32 + 2 * lc];
    uint2 u3 = *(const uint2*)&hw[(long)e3 * 32 + 2 * lc];
    acc4(u0, w0, a); acc4(u1, w1, a); acc4(u2, w2, a); acc4(u3, w3, a);
  }
#undef LS

#pragma unroll
  for (int i = 0; i < 4; ++i) a[i] += __shfl_xor(a[i], 16);
#pragma unroll
  for (int i = 0; i < 4; ++i) a[i] += __shfl_xor(a[i], 32);

  float dn = dinv[n];
  float sn = dn * dn;
  uint2 uh = *(const uint2*)&hw[(long)n * 32 + 2 * lc];
  float4 bb = *(const float4*)&bias[4 * lc];
  float o0 = fmaxf(fmaf(bflo_to_f(uh.x), sn, a[0] * dn) + bb.x, 0.f);
  float o1 = fmaxf(fmaf(bfhi_to_f(uh.x), sn, a[1] * dn) + bb.y, 0.f);
  float o2 = fmaxf(fmaf(bflo_to_f(uh.y), sn, a[2] * dn) + bb.z, 0.f);
  float o3 = fmaxf(fmaf(bfhi_to_f(uh.y), sn, a[3] * dn) + bb.w, 0.f);
  if (q == 0) {
    *(float4*)&out[(long)n * 64 + 4 * lc] = make_float4(o0, o1, o2, o3);
  }
}

// ---------------------------------------------------------------------------
extern "C" void kernel_launch(void* const* d_in, const int* in_sizes, int n_in,
                              void* d_out, int out_size, void* d_ws, size_t ws_size,
                              hipStream_t stream) {
  const float* x  = (const float*)d_in[0];
  const int*   ei = (const int*)d_in[1];
  const float* W1 = (const float*)d_in[2];
  const float* b1 = (const float*)d_in[3];
  const float* W2 = (const float*)d_in[4];
  const float* b2 = (const float*)d_in[5];
  float* out = (float*)d_out;

  const int* src = ei;             // edge_index[0]
  const int* dst = ei + N_EDGES;   // edge_index[1]

  // Workspace layout (bytes; every chunk is a multiple of 256B)
  char* ws = (char*)d_ws;
  int*   deg     = (int*)ws;                     ws += 50048 * 4;
  float* dinv    = (float*)ws;                   ws += 50048 * 4;
  int*   row_ptr = (int*)ws;                     ws += 50048 * 4;
  int*   bsums   = (int*)ws;                     ws += 64 * 4;
  int*   rank    = (int*)ws;                     ws += (size_t)N_EDGES * 4;
  int*   csr_src = (int*)ws;                     ws += (size_t)N_EDGES * 4;
  unsigned short* Wt1 = (unsigned short*)ws;     ws += 128 * 128 * 2;
  unsigned short* Wt2 = (unsigned short*)ws;     ws += 64 * 128 * 2;
  unsigned short* hw1 = (unsigned short*)ws;     ws += (size_t)N_NODES * 128 * 2;
  unsigned*       h1  = (unsigned*)ws;           ws += (size_t)N_NODES * 64 * 4;
  unsigned short* hw2 = (unsigned short*)ws;     ws += (size_t)N_NODES * 64 * 2;

  // ---- Init (zero deg + weight conversion) ----
  init_kernel<<<49 + 96, 256, 0, stream>>>(deg, W1, W2, Wt1, Wt2);

  // ---- hist (8 edges/thread, batched atomics) co-scheduled with GEMM1 ----
  hist_gemm1_kernel<<<GEMM1_TILES * 2, 256, 0, stream>>>(
      dst, deg, rank, x, Wt1, hw1);

  // ---- CSR scan + place ----
  scan_partial_kernel<<<NB, SCAN_B, 0, stream>>>(deg, bsums, dinv);
  scan_final_kernel<<<NB, SCAN_B, 0, stream>>>(deg, bsums, row_ptr);
  place_kernel<<<391, 256, 0, stream>>>(src, dst, rank, row_ptr, csr_src);

  // ---- Layer 1 aggregation ----
  agg128_kernel<<<(N_NODES * 64 + 255) / 256, 256, 0, stream>>>(
      row_ptr, csr_src, dinv, (const unsigned*)hw1, b1, h1);

  // ---- Layer 2 GEMM ----
  gemm2_kernel<<<GEMM1_TILES, 256, 0, stream>>>(
      (const unsigned short*)h1, Wt2, hw2);

  // ---- Layer 2 aggregation ----
  agg64_kernel<<<(N_NODES * 64 + 255) / 256, 256, 0, stream>>>(
      row_ptr, csr_src, dinv, (const unsigned*)hw2, b2, out);
}